// Round 12
// baseline (568.807 us; speedup 1.0000x reference)
//
#include <hip/hip_runtime.h>
#include <math.h>

#define NA 10000
#define NE 250000
#define FD 128
#define NRBF 20
#define RCUT 5.0f
#define AB 8    // atoms per mixint block (1250 blocks -> ~4.9/CU)

typedef _Float16 h16;
typedef __attribute__((ext_vector_type(8))) _Float16 half8;
typedef __attribute__((ext_vector_type(2))) _Float16 half2v;
typedef __attribute__((ext_vector_type(4))) float f32x4;

static __device__ __forceinline__ half8 f32x8_to_h8(const float* p) {
    float4 a = *(const float4*)p;
    float4 b = *(const float4*)(p + 4);
    half8 r;
    r[0] = (h16)a.x; r[1] = (h16)a.y; r[2] = (h16)a.z; r[3] = (h16)a.w;
    r[4] = (h16)b.x; r[5] = (h16)b.y; r[6] = (h16)b.z; r[7] = (h16)b.w;
    return r;
}
static __device__ __forceinline__ float silu(float v) {
    return v / (1.f + expf(-v));
}

// ====== mega setup: geom (compaction, own binary search) | weights | csr ====
// blocks [0,977): geom, [977,3137): weight prep, [3137,3177): row_start
// cnt[] must be zeroed before this kernel (hipMemsetAsync in launch).
__global__ __launch_bounds__(256) void setup_kernel(
    const float* __restrict__ R, const int* __restrict__ idx_i,
    const int* __restrict__ idx_j, const float* __restrict__ offsets,
    float* __restrict__ dir, h16* __restrict__ ph, int* __restrict__ jdx,
    int* __restrict__ row_start, int* __restrict__ cnt,
    const float* __restrict__ int_W1, const float* __restrict__ int_W2,
    const float* __restrict__ mix_Wmu, const float* __restrict__ mix_W1,
    const float* __restrict__ mix_W2,
    h16* __restrict__ W1t, h16* __restrict__ W2t, h16* __restrict__ WmuT,
    h16* __restrict__ mW1t, h16* __restrict__ mW2t,
    const float* __restrict__ filt_W, const float* __restrict__ filt_b,
    h16* __restrict__ fwt)
{
    const int b = blockIdx.x;
    if (b < 977) {
        int e = b * 256 + threadIdx.x;
        if (e >= NE) return;
        int i = idx_i[e], j = idx_j[e];
        float rx = R[j * 3 + 0] - R[i * 3 + 0] + offsets[e * 3 + 0];
        float ry = R[j * 3 + 1] - R[i * 3 + 1] + offsets[e * 3 + 1];
        float rz = R[j * 3 + 2] - R[i * 3 + 2] + offsets[e * 3 + 2];
        float d = sqrtf(rx * rx + ry * ry + rz * rz);
        if (d >= RCUT) return;                 // dead edge: Wij == 0 exactly
        float inv = 1.f / d;
        float fcut = 0.5f * (cosf(d * (3.14159265358979323846f / RCUT)) + 1.f);
        // own lower_bound(idx_i, i) = base of atom i's edge range
        int lo = 0, hi = NE;
        while (lo < hi) {
            int mid = (lo + hi) >> 1;
            if (idx_i[mid] < i) lo = mid + 1; else hi = mid;
        }
        int pos = atomicAdd(&cnt[i], 1);
        int s = lo + pos;
        *(float4*)&dir[(size_t)s * 4] = make_float4(rx * inv, ry * inv, rz * inv, 0.f);
        jdx[s] = j;
        h16* pp = ph + (size_t)s * 32;
        const float delta = RCUT / 19.f;
        const float coeff = -0.5f / (delta * delta);
#pragma unroll
        for (int r = 0; r < NRBF; ++r) {
            float dc = d - (float)r * delta;
            pp[r] = (h16)(expf(coeff * dc * dc) * fcut);
        }
        pp[20] = (h16)fcut;
#pragma unroll
        for (int r = 21; r < 32; ++r) pp[r] = (h16)0.f;
    } else if (b < 3137) {
        int idx = (b - 977) * 256 + threadIdx.x;
        if (idx < 49152) {                       // int_W1: K=128,N=128
            int bt = idx >> 14, rem = idx & 16383;
            int nn = rem >> 7, kk = rem & 127;
            W1t[idx] = (h16)int_W1[(size_t)bt * 16384 + kk * 128 + nn];
        } else if ((idx -= 49152) < 147456) {    // int_W2: K=128,N=384
            int bt = idx / 49152, rem = idx - bt * 49152;
            int nn = rem >> 7, kk = rem & 127;
            W2t[idx] = (h16)int_W2[(size_t)bt * 49152 + kk * 384 + nn];
        } else if ((idx -= 147456) < 98304) {    // mix_Wmu: K=128,N=256
            int bt = idx >> 15, rem = idx & 32767;
            int nn = rem >> 7, kk = rem & 127;
            WmuT[idx] = (h16)mix_Wmu[(size_t)bt * 32768 + kk * 256 + nn];
        } else if ((idx -= 98304) < 98304) {     // mix_W1: K=256,N=128
            int bt = idx >> 15, rem = idx & 32767;
            int nn = rem >> 8, kk = rem & 255;
            mW1t[idx] = (h16)mix_W1[(size_t)bt * 32768 + kk * 128 + nn];
        } else if ((idx -= 98304) < 147456) {    // mix_W2: K=128,N=384
            int bt = idx / 49152, rem = idx - bt * 49152;
            int nn = rem >> 7, kk = rem & 127;
            mW2t[idx] = (h16)mix_W2[(size_t)bt * 49152 + kk * 384 + nn];
        } else if ((idx -= 147456) < 12288) {    // fwt [384][32]
            int nn = idx >> 5, kk = idx & 31;
            float v = 0.f;
            if (kk < 20) v = filt_W[kk * 384 + nn];
            else if (kk == 20) v = filt_b[nn];
            fwt[idx] = (h16)v;
        }
    } else {
        int n = (b - 3137) * 256 + threadIdx.x;
        if (n > NA) return;
        int lo = 0, hi = NE;
        while (lo < hi) {
            int mid = (lo + hi) >> 1;
            if (idx_i[mid] < n) lo = mid + 1; else hi = mid;
        }
        row_start[n] = lo;
    }
}

// ====== iteration-0 interaction MLP ======
__global__ __launch_bounds__(256) void intmlp0_kernel(
    const int* __restrict__ Z, const float* __restrict__ emb, float* __restrict__ q,
    const h16* __restrict__ W1t, const float* __restrict__ b1,
    const h16* __restrict__ W2t, const float* __restrict__ b2, h16* __restrict__ x16)
{
    __shared__ h16 Hs[16 * 136];
    const int tid = threadIdx.x;
    const int wave = tid >> 6, lane = tid & 63;
    const int ar = lane & 15, kg = lane >> 4;
    const size_t row0 = (size_t)blockIdx.x * 16;

    {
        int a = tid >> 4, f0 = (tid & 15) * 8;
        const float* src = emb + (size_t)Z[row0 + a] * 128 + f0;
        float4 v0 = *(const float4*)src;
        float4 v1 = *(const float4*)(src + 4);
        *(float4*)&q[(row0 + a) * 128 + f0] = v0;
        *(float4*)&q[(row0 + a) * 128 + f0 + 4] = v1;
    }
    const int zr = Z[row0 + ar];
    f32x4 a1[2] = {};
    for (int ks = 0; ks < 128; ks += 32) {
        int k = ks + kg * 8;
        half8 af = f32x8_to_h8(emb + (size_t)zr * 128 + k);
#pragma unroll
        for (int tt = 0; tt < 2; ++tt) {
            int t = wave * 2 + tt;
            half8 bf = *(const half8*)&W1t[(size_t)(t * 16 + ar) * 128 + k];
            a1[tt] = __builtin_amdgcn_mfma_f32_16x16x32_f16(af, bf, a1[tt], 0, 0, 0);
        }
    }
#pragma unroll
    for (int tt = 0; tt < 2; ++tt) {
        int col = (wave * 2 + tt) * 16 + ar;
        float bb = b1[col];
#pragma unroll
        for (int r = 0; r < 4; ++r)
            Hs[(kg * 4 + r) * 136 + col] = (h16)silu(a1[tt][r] + bb);
    }
    __syncthreads();
    f32x4 a2[6] = {};
    for (int ks = 0; ks < 128; ks += 32) {
        int k = ks + kg * 8;
        half8 af = *(const half8*)&Hs[ar * 136 + k];
#pragma unroll
        for (int tt = 0; tt < 6; ++tt) {
            int t = wave * 6 + tt;
            half8 bf = *(const half8*)&W2t[(size_t)(t * 16 + ar) * 128 + k];
            a2[tt] = __builtin_amdgcn_mfma_f32_16x16x32_f16(af, bf, a2[tt], 0, 0, 0);
        }
    }
#pragma unroll
    for (int tt = 0; tt < 6; ++tt) {
        int col = (wave * 6 + tt) * 16 + ar;
        float bb = b2[col];
#pragma unroll
        for (int r = 0; r < 4; ++r)
            x16[(row0 + kg * 4 + r) * 384 + col] = (h16)(a2[tt][r] + bb);
    }
}

// ====== edge kernel (unchanged from R11 — proven) ======
template<bool HAS_MU>
__global__ __launch_bounds__(128) void edge_kernel(
    const float* __restrict__ dir, const h16* __restrict__ ph,
    const h16* __restrict__ fwt,
    const int* __restrict__ row_start, const int* __restrict__ cnt,
    const int* __restrict__ jdx,
    const h16* __restrict__ x16, const h16* __restrict__ mu16p,
    const float* __restrict__ mup, float* __restrict__ mun,
    h16* __restrict__ mu16n, float* __restrict__ q)
{
    const int n = blockIdx.x, f = threadIdx.x;
    half2v fa[12], fb[12], fc[12];
    {
        const half8* pa = (const half8*)(fwt + (size_t)f * 32);
        const half8* pb = (const half8*)(fwt + (size_t)(128 + f) * 32);
#pragma unroll
        for (int r = 0; r < 3; ++r) {
            *(half8*)&fa[r * 4] = pa[r];
            *(half8*)&fb[r * 4] = pb[r];
        }
        if (HAS_MU) {
            const half8* pc = (const half8*)(fwt + (size_t)(256 + f) * 32);
#pragma unroll
            for (int r = 0; r < 3; ++r)
                *(half8*)&fc[r * 4] = pc[r];
        }
    }
    float accq = 0.f, am0 = 0.f, am1 = 0.f, am2 = 0.f;
    const int e0 = row_start[n], e1 = e0 + cnt[n];
    for (int e = e0; e < e1; ++e) {
        half2v pr[12];
        const h16* pb8 = ph + (size_t)e * 32;
        *(half8*)&pr[0] = *(const half8*)pb8;
        *(half8*)&pr[4] = *(const half8*)(pb8 + 8);
        *(half8*)&pr[8] = *(const half8*)(pb8 + 16);
        half2v A0 = {(h16)0.f, (h16)0.f}, A1 = A0, A2 = A0;
#pragma unroll
        for (int r = 0; r < 11; ++r) {
            A0 = pr[r] * fa[r] + A0;
            A1 = pr[r] * fb[r] + A1;
            if (HAS_MU) A2 = pr[r] * fc[r] + A2;
        }
        float w0 = (float)A0[0] + (float)A0[1];
        float w1 = (float)A1[0] + (float)A1[1];
        int j = jdx[e];
        float4 g = *(const float4*)&dir[(size_t)e * 4];
        const h16* xb = x16 + (size_t)j * 384;
        float x0 = (float)xb[f], x1 = (float)xb[128 + f];
        accq = fmaf(w0, x0, accq);
        float xw1 = w1 * x1;
        if (HAS_MU) {
            float w2 = (float)A2[0] + (float)A2[1];
            float x2 = (float)xb[256 + f];
            float xw2 = w2 * x2;
            const h16* mb = mu16p + (size_t)j * 384;
            am0 += xw1 * g.x + xw2 * (float)mb[f];
            am1 += xw1 * g.y + xw2 * (float)mb[128 + f];
            am2 += xw1 * g.z + xw2 * (float)mb[256 + f];
        } else {
            am0 = fmaf(xw1, g.x, am0);
            am1 = fmaf(xw1, g.y, am1);
            am2 = fmaf(xw1, g.z, am2);
        }
    }
    q[(size_t)n * FD + f] += accq;
    size_t b = (size_t)n * 384;
    float m0 = (HAS_MU ? mup[b + f] : 0.f) + am0;
    float m1 = (HAS_MU ? mup[b + 128 + f] : 0.f) + am1;
    float m2 = (HAS_MU ? mup[b + 256 + f] : 0.f) + am2;
    mun[b + f] = m0; mun[b + 128 + f] = m1; mun[b + 256 + f] = m2;
    mu16n[b + f] = (h16)m0; mu16n[b + 128 + f] = (h16)m1; mu16n[b + 256 + f] = (h16)m2;
}

// ====== fused mixing (+ optional next intmlp), 8 atoms/block ======
// 1250 blocks -> ~4.9/CU; 16-row MFMA tiles half-wasted (free: latency-bound).
// Garbage rows are contained in LDS; all global reads/writes guarded to AB atoms.
__global__ __launch_bounds__(256) void mixint_kernel(
    const h16* __restrict__ mu16n, const h16* __restrict__ WmuT,
    const h16* __restrict__ W1t, const float* __restrict__ b1,
    const h16* __restrict__ W2t, const float* __restrict__ b2,
    float* __restrict__ q, float* __restrict__ mu, h16* __restrict__ mu16w,
    const h16* __restrict__ nW1t, const float* __restrict__ nb1,
    const h16* __restrict__ nW2t, const float* __restrict__ nb2,
    h16* __restrict__ x16)
{
    __shared__ h16 MM[32 * 264];   // rows 0..23 valid (8 atoms x 3 dirs)
    __shared__ h16 CT[16 * 264];
    __shared__ h16 Hs[16 * 136];
    const int tid = threadIdx.x;
    const int wave = tid >> 6, lane = tid & 63;
    const int ar = lane & 15, kg = lane >> 4;
    const size_t row0 = (size_t)blockIdx.x * AB;

    // phase 1: mumix = mu @ Wmu (24 valid rows x 256 cols) -> MM
    {
        f32x4 acc[2][4] = {};
        int aloc[2], dloc[2];
#pragma unroll
        for (int rt = 0; rt < 2; ++rt) {
            int rr = rt * 16 + ar;
            if (rr < 3 * AB) { aloc[rt] = rr / 3; dloc[rt] = rr - 3 * (rr / 3); }
            else             { aloc[rt] = AB - 1; dloc[rt] = 2; }
        }
        for (int ks = 0; ks < 128; ks += 32) {
            int k = ks + kg * 8;
            half8 afr[2];
#pragma unroll
            for (int rt = 0; rt < 2; ++rt)
                afr[rt] = *(const half8*)&mu16n[(row0 + aloc[rt]) * 384 + dloc[rt] * 128 + k];
#pragma unroll
            for (int ct = 0; ct < 4; ++ct) {
                int cc = wave * 4 + ct;
                half8 bf = *(const half8*)&WmuT[(size_t)(cc * 16 + ar) * 128 + k];
#pragma unroll
                for (int rt = 0; rt < 2; ++rt)
                    acc[rt][ct] = __builtin_amdgcn_mfma_f32_16x16x32_f16(afr[rt], bf, acc[rt][ct], 0, 0, 0);
            }
        }
#pragma unroll
        for (int rt = 0; rt < 2; ++rt)
#pragma unroll
            for (int ct = 0; ct < 4; ++ct) {
                int col = (wave * 4 + ct) * 16 + ar;
#pragma unroll
                for (int r = 0; r < 4; ++r)
                    MM[(rt * 16 + kg * 4 + r) * 264 + col] = (h16)acc[rt][ct][r];
            }
    }
    __syncthreads();

    // phase 2: ctx = [q, ||mu_V||] -> CT (rows >= AB duplicate row AB-1)
    {
        int a = tid >> 4, fi = (tid & 15) * 8;
        int aa = a < AB ? a : AB - 1;
        const float* qp = q + (row0 + aa) * 128 + fi;
        float4 q0 = *(const float4*)qp;
        float4 q1 = *(const float4*)(qp + 4);
        float qv[8] = {q0.x, q0.y, q0.z, q0.w, q1.x, q1.y, q1.z, q1.w};
#pragma unroll
        for (int jj = 0; jj < 8; ++jj) {
            int ff = fi + jj;
            float v0 = (float)MM[(aa * 3 + 0) * 264 + ff];
            float v1 = (float)MM[(aa * 3 + 1) * 264 + ff];
            float v2 = (float)MM[(aa * 3 + 2) * 264 + ff];
            CT[a * 264 + 128 + ff] = (h16)sqrtf(v0 * v0 + v1 * v1 + v2 * v2 + 1e-8f);
            CT[a * 264 + ff] = (h16)qv[jj];
        }
    }
    __syncthreads();

    // phase 3: h = silu(ctx @ mW1 + b1) -> Hs
    {
        f32x4 a1[2] = {};
        for (int ks = 0; ks < 256; ks += 32) {
            int k = ks + kg * 8;
            half8 af = *(const half8*)&CT[ar * 264 + k];
#pragma unroll
            for (int tt = 0; tt < 2; ++tt) {
                int t = wave * 2 + tt;
                half8 bf = *(const half8*)&W1t[(size_t)(t * 16 + ar) * 256 + k];
                a1[tt] = __builtin_amdgcn_mfma_f32_16x16x32_f16(af, bf, a1[tt], 0, 0, 0);
            }
        }
#pragma unroll
        for (int tt = 0; tt < 2; ++tt) {
            int col = (wave * 2 + tt) * 16 + ar;
            float bb = b1[col];
#pragma unroll
            for (int r = 0; r < 4; ++r)
                Hs[(kg * 4 + r) * 136 + col] = (h16)silu(a1[tt][r] + bb);
        }
    }
    __syncthreads();

    // phase 4: channel-split GEMM, accumulators in registers
    f32x4 aq[2] = {}, am[2] = {}, ag[2] = {};
    for (int ks = 0; ks < 128; ks += 32) {
        int k = ks + kg * 8;
        half8 af = *(const half8*)&Hs[ar * 136 + k];
#pragma unroll
        for (int p = 0; p < 2; ++p) {
            int t = wave * 2 + p;
            half8 bq = *(const half8*)&W2t[(size_t)(t * 16 + ar) * 128 + k];
            aq[p] = __builtin_amdgcn_mfma_f32_16x16x32_f16(af, bq, aq[p], 0, 0, 0);
            half8 bm = *(const half8*)&W2t[(size_t)((8 + t) * 16 + ar) * 128 + k];
            am[p] = __builtin_amdgcn_mfma_f32_16x16x32_f16(af, bm, am[p], 0, 0, 0);
            half8 bg = *(const half8*)&W2t[(size_t)((16 + t) * 16 + ar) * 128 + k];
            ag[p] = __builtin_amdgcn_mfma_f32_16x16x32_f16(af, bg, ag[p], 0, 0, 0);
        }
    }

    // phase 5: fused update from registers (guarded to AB atoms)
#pragma unroll
    for (int p = 0; p < 2; ++p) {
        int f = (wave * 2 + p) * 16 + ar;
        float bdq = b2[f], bdm = b2[128 + f], bdg = b2[256 + f];
#pragma unroll
        for (int r = 0; r < 4; ++r) {
            int aL = kg * 4 + r;
            if (aL < AB) {
                size_t n = row0 + aL;
                float dq  = aq[p][r] + bdq;
                float dm  = am[p][r] + bdm;
                float dqm = ag[p][r] + bdg;
                float v0 = (float)MM[(aL * 3 + 0) * 264 + f], w0 = (float)MM[(aL * 3 + 0) * 264 + 128 + f];
                float v1 = (float)MM[(aL * 3 + 1) * 264 + f], w1 = (float)MM[(aL * 3 + 1) * 264 + 128 + f];
                float v2 = (float)MM[(aL * 3 + 2) * 264 + f], w2 = (float)MM[(aL * 3 + 2) * 264 + 128 + f];
                float sv = v0 * w0 + v1 * w1 + v2 * w2;
                float qn = q[n * 128 + f] + dq + dqm * sv;
                q[n * 128 + f] = qn;
                CT[aL * 264 + f] = (h16)qn;
                size_t b = n * 384 + f;
                float m0 = mu[b] + dm * w0;
                float m1 = mu[b + 128] + dm * w1;
                float m2 = mu[b + 256] + dm * w2;
                mu[b] = m0; mu[b + 128] = m1; mu[b + 256] = m2;
                mu16w[b] = (h16)m0; mu16w[b + 128] = (h16)m1; mu16w[b + 256] = (h16)m2;
            }
        }
    }
    if (!nW1t) return;
    __syncthreads();

    // tail: next-iteration interaction MLP from CT (new q)
    {
        f32x4 a1[2] = {};
        for (int ks = 0; ks < 128; ks += 32) {
            int k = ks + kg * 8;
            half8 af = *(const half8*)&CT[ar * 264 + k];
#pragma unroll
            for (int tt = 0; tt < 2; ++tt) {
                int t = wave * 2 + tt;
                half8 bf = *(const half8*)&nW1t[(size_t)(t * 16 + ar) * 128 + k];
                a1[tt] = __builtin_amdgcn_mfma_f32_16x16x32_f16(af, bf, a1[tt], 0, 0, 0);
            }
        }
#pragma unroll
        for (int tt = 0; tt < 2; ++tt) {
            int col = (wave * 2 + tt) * 16 + ar;
            float bb = nb1[col];
#pragma unroll
            for (int r = 0; r < 4; ++r)
                Hs[(kg * 4 + r) * 136 + col] = (h16)silu(a1[tt][r] + bb);
        }
        __syncthreads();
        f32x4 a2[6] = {};
        for (int ks = 0; ks < 128; ks += 32) {
            int k = ks + kg * 8;
            half8 af = *(const half8*)&Hs[ar * 136 + k];
#pragma unroll
            for (int tt = 0; tt < 6; ++tt) {
                int t = wave * 6 + tt;
                half8 bf = *(const half8*)&nW2t[(size_t)(t * 16 + ar) * 128 + k];
                a2[tt] = __builtin_amdgcn_mfma_f32_16x16x32_f16(af, bf, a2[tt], 0, 0, 0);
            }
        }
#pragma unroll
        for (int tt = 0; tt < 6; ++tt) {
            int col = (wave * 6 + tt) * 16 + ar;
            float bb = nb2[col];
#pragma unroll
            for (int r = 0; r < 4; ++r) {
                int aL = kg * 4 + r;
                if (aL < AB)
                    x16[(row0 + aL) * 384 + col] = (h16)(a2[tt][r] + bb);
            }
        }
    }
}

// ====== launch ======
extern "C" void kernel_launch(void* const* d_in, const int* in_sizes, int n_in,
                              void* d_out, int out_size, void* d_ws, size_t ws_size,
                              hipStream_t stream)
{
    const int*   Z       = (const int*)d_in[0];
    const float* R       = (const float*)d_in[1];
    const int*   idx_i   = (const int*)d_in[2];
    const int*   idx_j   = (const int*)d_in[3];
    const float* offsets = (const float*)d_in[4];
    const float* emb     = (const float*)d_in[5];
    const float* filt_W  = (const float*)d_in[6];
    const float* filt_b  = (const float*)d_in[7];
    const float* int_W1  = (const float*)d_in[8];
    const float* int_b1  = (const float*)d_in[9];
    const float* int_W2  = (const float*)d_in[10];
    const float* int_b2  = (const float*)d_in[11];
    const float* mix_Wmu = (const float*)d_in[12];
    const float* mix_W1  = (const float*)d_in[13];
    const float* mix_b1  = (const float*)d_in[14];
    const float* mix_W2  = (const float*)d_in[15];
    const float* mix_b2  = (const float*)d_in[16];

    float* q_out  = (float*)d_out;
    float* mu_out = (float*)d_out + (size_t)NA * FD;

    char* base = (char*)d_ws;
    size_t o = 0;
    auto alloc = [&](size_t bytes) -> void* {
        void* p = base + o;
        o += (bytes + 255) & ~(size_t)255;
        return p;
    };
    float* dir    = (float*)alloc((size_t)NE * 4 * 4);
    h16*   ph     = (h16*)alloc((size_t)NE * 32 * 2);
    int*   jdx    = (int*)alloc((size_t)NE * 4);
    h16*   x16    = (h16*)alloc((size_t)NA * 384 * 2);
    h16*   mu16a  = (h16*)alloc((size_t)NA * 384 * 2);
    h16*   mu16b  = (h16*)alloc((size_t)NA * 384 * 2);
    float* mu_ws  = (float*)alloc((size_t)NA * 384 * 4);
    h16*   W1t    = (h16*)alloc((size_t)3 * 128 * 128 * 2);
    h16*   W2t    = (h16*)alloc((size_t)3 * 384 * 128 * 2);
    h16*   WmuT   = (h16*)alloc((size_t)3 * 256 * 128 * 2);
    h16*   mW1t   = (h16*)alloc((size_t)3 * 128 * 256 * 2);
    h16*   mW2t   = (h16*)alloc((size_t)3 * 384 * 128 * 2);
    h16*   fwt    = (h16*)alloc((size_t)384 * 32 * 2);
    int*   row_st = (int*)alloc((size_t)(NA + 1) * 4);
    int*   cnt    = (int*)alloc((size_t)NA * 4);

    hipMemsetAsync(cnt, 0, (size_t)NA * 4, stream);
    setup_kernel<<<3177, 256, 0, stream>>>(R, idx_i, idx_j, offsets, dir, ph, jdx,
                                           row_st, cnt,
                                           int_W1, int_W2, mix_Wmu, mix_W1, mix_W2,
                                           W1t, W2t, WmuT, mW1t, mW2t,
                                           filt_W, filt_b, fwt);

    // iteration 0
    intmlp0_kernel<<<NA / 16, 256, 0, stream>>>(Z, emb, q_out,
                                                W1t, int_b1, W2t, int_b2, x16);
    edge_kernel<false><<<NA, 128, 0, stream>>>(dir, ph, fwt, row_st, cnt, jdx,
                                               x16, nullptr, nullptr, mu_out, mu16b, q_out);
    mixint_kernel<<<NA / AB, 256, 0, stream>>>(
        mu16b, WmuT, mW1t, mix_b1, mW2t, mix_b2, q_out, mu_out, mu16b,
        W1t + 16384, int_b1 + 128, W2t + 49152, int_b2 + 384, x16);

    // iteration 1
    edge_kernel<true><<<NA, 128, 0, stream>>>(dir, ph, fwt, row_st, cnt, jdx,
                                              x16, mu16b, mu_out, mu_ws, mu16a, q_out);
    mixint_kernel<<<NA / AB, 256, 0, stream>>>(
        mu16a, WmuT + 32768, mW1t + 32768, mix_b1 + 128, mW2t + 49152, mix_b2 + 384,
        q_out, mu_ws, mu16a,
        W1t + 32768, int_b1 + 256, W2t + 98304, int_b2 + 768, x16);

    // iteration 2
    edge_kernel<true><<<NA, 128, 0, stream>>>(dir, ph, fwt, row_st, cnt, jdx,
                                              x16, mu16a, mu_ws, mu_out, mu16b, q_out);
    mixint_kernel<<<NA / AB, 256, 0, stream>>>(
        mu16b, WmuT + 65536, mW1t + 65536, mix_b1 + 256, mW2t + 98304, mix_b2 + 768,
        q_out, mu_out, mu16b,
        nullptr, nullptr, nullptr, nullptr, nullptr);
}

// Round 13
// 473.615 us; speedup vs baseline: 1.2010x; 1.2010x over previous
//
#include <hip/hip_runtime.h>
#include <math.h>

#define NA 10000
#define NE 250000
#define FD 128
#define NRBF 20
#define RCUT 5.0f

typedef _Float16 h16;
typedef __attribute__((ext_vector_type(8))) _Float16 half8;
typedef __attribute__((ext_vector_type(2))) _Float16 half2v;
typedef __attribute__((ext_vector_type(4))) float f32x4;

static __device__ __forceinline__ half8 f32x8_to_h8(const float* p) {
    float4 a = *(const float4*)p;
    float4 b = *(const float4*)(p + 4);
    half8 r;
    r[0] = (h16)a.x; r[1] = (h16)a.y; r[2] = (h16)a.z; r[3] = (h16)a.w;
    r[4] = (h16)b.x; r[5] = (h16)b.y; r[6] = (h16)b.z; r[7] = (h16)b.w;
    return r;
}
static __device__ __forceinline__ float silu(float v) {
    return v / (1.f + expf(-v));
}

// ====== CSR row offsets + compaction counter zeroing ======
__global__ void csr_kernel(const int* __restrict__ idx_i, int* __restrict__ row_start,
                           int* __restrict__ cnt)
{
    int n = blockIdx.x * 256 + threadIdx.x;
    if (n > NA) return;
    int lo = 0, hi = NE;
    while (lo < hi) {
        int mid = (lo + hi) >> 1;
        if (idx_i[mid] < n) lo = mid + 1; else hi = mid;
    }
    row_start[n] = lo;
    if (n < NA) cnt[n] = 0;
}

// ====== mega setup: geom (dead-edge compaction) | weight prep ======
__global__ __launch_bounds__(256) void setup_kernel(
    const float* __restrict__ R, const int* __restrict__ idx_i,
    const int* __restrict__ idx_j, const float* __restrict__ offsets,
    float* __restrict__ dir, h16* __restrict__ ph, int* __restrict__ jdx,
    const int* __restrict__ row_start, int* __restrict__ cnt,
    const float* __restrict__ int_W1, const float* __restrict__ int_W2,
    const float* __restrict__ mix_Wmu, const float* __restrict__ mix_W1,
    const float* __restrict__ mix_W2,
    h16* __restrict__ W1t, h16* __restrict__ W2t, h16* __restrict__ WmuT,
    h16* __restrict__ mW1t, h16* __restrict__ mW2t,
    const float* __restrict__ filt_W, const float* __restrict__ filt_b,
    h16* __restrict__ fwt)
{
    const int b = blockIdx.x;
    if (b < 977) {
        int e = b * 256 + threadIdx.x;
        if (e >= NE) return;
        int i = idx_i[e], j = idx_j[e];
        float rx = R[j * 3 + 0] - R[i * 3 + 0] + offsets[e * 3 + 0];
        float ry = R[j * 3 + 1] - R[i * 3 + 1] + offsets[e * 3 + 1];
        float rz = R[j * 3 + 2] - R[i * 3 + 2] + offsets[e * 3 + 2];
        float d = sqrtf(rx * rx + ry * ry + rz * rz);
        if (d >= RCUT) return;                 // dead edge: Wij == 0 exactly
        float inv = 1.f / d;
        float fcut = 0.5f * (cosf(d * (3.14159265358979323846f / RCUT)) + 1.f);
        int pos = atomicAdd(&cnt[i], 1);
        int s = row_start[i] + pos;
        *(float4*)&dir[(size_t)s * 4] = make_float4(rx * inv, ry * inv, rz * inv, 0.f);
        jdx[s] = j;
        h16* pp = ph + (size_t)s * 32;
        const float delta = RCUT / 19.f;
        const float coeff = -0.5f / (delta * delta);
#pragma unroll
        for (int r = 0; r < NRBF; ++r) {
            float dc = d - (float)r * delta;
            pp[r] = (h16)(expf(coeff * dc * dc) * fcut);
        }
        pp[20] = (h16)fcut;
#pragma unroll
        for (int r = 21; r < 32; ++r) pp[r] = (h16)0.f;
    } else {
        int idx = (b - 977) * 256 + threadIdx.x;
        if (idx < 49152) {                       // int_W1: K=128,N=128
            int bt = idx >> 14, rem = idx & 16383;
            int nn = rem >> 7, kk = rem & 127;
            W1t[idx] = (h16)int_W1[(size_t)bt * 16384 + kk * 128 + nn];
        } else if ((idx -= 49152) < 147456) {    // int_W2: K=128,N=384
            int bt = idx / 49152, rem = idx - bt * 49152;
            int nn = rem >> 7, kk = rem & 127;
            W2t[idx] = (h16)int_W2[(size_t)bt * 49152 + kk * 384 + nn];
        } else if ((idx -= 147456) < 98304) {    // mix_Wmu: K=128,N=256
            int bt = idx >> 15, rem = idx & 32767;
            int nn = rem >> 7, kk = rem & 127;
            WmuT[idx] = (h16)mix_Wmu[(size_t)bt * 32768 + kk * 256 + nn];
        } else if ((idx -= 98304) < 98304) {     // mix_W1: K=256,N=128
            int bt = idx >> 15, rem = idx & 32767;
            int nn = rem >> 8, kk = rem & 255;
            mW1t[idx] = (h16)mix_W1[(size_t)bt * 32768 + kk * 128 + nn];
        } else if ((idx -= 98304) < 147456) {    // mix_W2: K=128,N=384
            int bt = idx / 49152, rem = idx - bt * 49152;
            int nn = rem >> 7, kk = rem & 127;
            mW2t[idx] = (h16)mix_W2[(size_t)bt * 49152 + kk * 384 + nn];
        } else if ((idx -= 147456) < 12288) {    // fwt [384][32]
            int nn = idx >> 5, kk = idx & 31;
            float v = 0.f;
            if (kk < 20) v = filt_W[kk * 384 + nn];
            else if (kk == 20) v = filt_b[nn];
            fwt[idx] = (h16)v;
        }
    }
}

// ====== iteration-0 interaction MLP ======
__global__ __launch_bounds__(256) void intmlp0_kernel(
    const int* __restrict__ Z, const float* __restrict__ emb, float* __restrict__ q,
    const h16* __restrict__ W1t, const float* __restrict__ b1,
    const h16* __restrict__ W2t, const float* __restrict__ b2, h16* __restrict__ x16)
{
    __shared__ h16 Hs[16 * 136];
    const int tid = threadIdx.x;
    const int wave = tid >> 6, lane = tid & 63;
    const int ar = lane & 15, kg = lane >> 4;
    const size_t row0 = (size_t)blockIdx.x * 16;

    {
        int a = tid >> 4, f0 = (tid & 15) * 8;
        const float* src = emb + (size_t)Z[row0 + a] * 128 + f0;
        float4 v0 = *(const float4*)src;
        float4 v1 = *(const float4*)(src + 4);
        *(float4*)&q[(row0 + a) * 128 + f0] = v0;
        *(float4*)&q[(row0 + a) * 128 + f0 + 4] = v1;
    }
    const int zr = Z[row0 + ar];
    f32x4 a1[2] = {};
    for (int ks = 0; ks < 128; ks += 32) {
        int k = ks + kg * 8;
        half8 af = f32x8_to_h8(emb + (size_t)zr * 128 + k);
#pragma unroll
        for (int tt = 0; tt < 2; ++tt) {
            int t = wave * 2 + tt;
            half8 bf = *(const half8*)&W1t[(size_t)(t * 16 + ar) * 128 + k];
            a1[tt] = __builtin_amdgcn_mfma_f32_16x16x32_f16(af, bf, a1[tt], 0, 0, 0);
        }
    }
#pragma unroll
    for (int tt = 0; tt < 2; ++tt) {
        int col = (wave * 2 + tt) * 16 + ar;
        float bb = b1[col];
#pragma unroll
        for (int r = 0; r < 4; ++r)
            Hs[(kg * 4 + r) * 136 + col] = (h16)silu(a1[tt][r] + bb);
    }
    __syncthreads();
    f32x4 a2[6] = {};
    for (int ks = 0; ks < 128; ks += 32) {
        int k = ks + kg * 8;
        half8 af = *(const half8*)&Hs[ar * 136 + k];
#pragma unroll
        for (int tt = 0; tt < 6; ++tt) {
            int t = wave * 6 + tt;
            half8 bf = *(const half8*)&W2t[(size_t)(t * 16 + ar) * 128 + k];
            a2[tt] = __builtin_amdgcn_mfma_f32_16x16x32_f16(af, bf, a2[tt], 0, 0, 0);
        }
    }
#pragma unroll
    for (int tt = 0; tt < 6; ++tt) {
        int col = (wave * 6 + tt) * 16 + ar;
        float bb = b2[col];
#pragma unroll
        for (int r = 0; r < 4; ++r)
            x16[(row0 + kg * 4 + r) * 384 + col] = (h16)(a2[tt][r] + bb);
    }
}

// ====== edge kernel (R11-proven: lane = feature, serial compacted edges) ====
template<bool HAS_MU>
__global__ __launch_bounds__(128) void edge_kernel(
    const float* __restrict__ dir, const h16* __restrict__ ph,
    const h16* __restrict__ fwt,
    const int* __restrict__ row_start, const int* __restrict__ cnt,
    const int* __restrict__ jdx,
    const h16* __restrict__ x16, const h16* __restrict__ mu16p,
    const float* __restrict__ mup, float* __restrict__ mun,
    h16* __restrict__ mu16n, float* __restrict__ q)
{
    const int n = blockIdx.x, f = threadIdx.x;
    half2v fa[12], fb[12], fc[12];
    {
        const half8* pa = (const half8*)(fwt + (size_t)f * 32);
        const half8* pb = (const half8*)(fwt + (size_t)(128 + f) * 32);
#pragma unroll
        for (int r = 0; r < 3; ++r) {
            *(half8*)&fa[r * 4] = pa[r];
            *(half8*)&fb[r * 4] = pb[r];
        }
        if (HAS_MU) {
            const half8* pc = (const half8*)(fwt + (size_t)(256 + f) * 32);
#pragma unroll
            for (int r = 0; r < 3; ++r)
                *(half8*)&fc[r * 4] = pc[r];
        }
    }
    float accq = 0.f, am0 = 0.f, am1 = 0.f, am2 = 0.f;
    const int e0 = row_start[n], e1 = e0 + cnt[n];
    for (int e = e0; e < e1; ++e) {
        half2v pr[12];
        const h16* pb8 = ph + (size_t)e * 32;
        *(half8*)&pr[0] = *(const half8*)pb8;
        *(half8*)&pr[4] = *(const half8*)(pb8 + 8);
        *(half8*)&pr[8] = *(const half8*)(pb8 + 16);
        half2v A0 = {(h16)0.f, (h16)0.f}, A1 = A0, A2 = A0;
#pragma unroll
        for (int r = 0; r < 11; ++r) {
            A0 = pr[r] * fa[r] + A0;
            A1 = pr[r] * fb[r] + A1;
            if (HAS_MU) A2 = pr[r] * fc[r] + A2;
        }
        float w0 = (float)A0[0] + (float)A0[1];
        float w1 = (float)A1[0] + (float)A1[1];
        int j = jdx[e];
        float4 g = *(const float4*)&dir[(size_t)e * 4];
        const h16* xb = x16 + (size_t)j * 384;
        float x0 = (float)xb[f], x1 = (float)xb[128 + f];
        accq = fmaf(w0, x0, accq);
        float xw1 = w1 * x1;
        if (HAS_MU) {
            float w2 = (float)A2[0] + (float)A2[1];
            float x2 = (float)xb[256 + f];
            float xw2 = w2 * x2;
            const h16* mb = mu16p + (size_t)j * 384;
            am0 += xw1 * g.x + xw2 * (float)mb[f];
            am1 += xw1 * g.y + xw2 * (float)mb[128 + f];
            am2 += xw1 * g.z + xw2 * (float)mb[256 + f];
        } else {
            am0 = fmaf(xw1, g.x, am0);
            am1 = fmaf(xw1, g.y, am1);
            am2 = fmaf(xw1, g.z, am2);
        }
    }
    q[(size_t)n * FD + f] += accq;
    size_t b = (size_t)n * 384;
    float m0 = (HAS_MU ? mup[b + f] : 0.f) + am0;
    float m1 = (HAS_MU ? mup[b + 128 + f] : 0.f) + am1;
    float m2 = (HAS_MU ? mup[b + 256 + f] : 0.f) + am2;
    mun[b + f] = m0; mun[b + 128 + f] = m1; mun[b + 256 + f] = m2;
    mu16n[b + f] = (h16)m0; mu16n[b + 128 + f] = (h16)m1; mu16n[b + 256 + f] = (h16)m2;
}

// ====== fused mixing (R9-proven XM version, 16 atoms/block) ======
__global__ __launch_bounds__(256) void mixint_kernel(
    const h16* __restrict__ mu16n, const h16* __restrict__ WmuT,
    const h16* __restrict__ W1t, const float* __restrict__ b1,
    const h16* __restrict__ W2t, const float* __restrict__ b2,
    float* __restrict__ q, float* __restrict__ mu, h16* __restrict__ mu16w,
    const h16* __restrict__ nW1t, const float* __restrict__ nb1,
    const h16* __restrict__ nW2t, const float* __restrict__ nb2,
    h16* __restrict__ x16)
{
    __shared__ h16 MM[48 * 264];
    __shared__ h16 CT[16 * 264];
    __shared__ h16 Hs[16 * 136];
    __shared__ h16 XM[16 * 392];
    const int tid = threadIdx.x;
    const int wave = tid >> 6, lane = tid & 63;
    const int ar = lane & 15, kg = lane >> 4;
    const size_t row0 = (size_t)blockIdx.x * 16;

    {
        f32x4 acc[3][4] = {};
        int aloc[3], dloc[3];
#pragma unroll
        for (int rt = 0; rt < 3; ++rt) {
            int rr = rt * 16 + ar;
            aloc[rt] = rr / 3;
            dloc[rt] = rr - 3 * aloc[rt];
        }
        for (int ks = 0; ks < 128; ks += 32) {
            int k = ks + kg * 8;
            half8 afr[3];
#pragma unroll
            for (int rt = 0; rt < 3; ++rt)
                afr[rt] = *(const half8*)&mu16n[(row0 + aloc[rt]) * 384 + dloc[rt] * 128 + k];
#pragma unroll
            for (int ct = 0; ct < 4; ++ct) {
                int cc = wave * 4 + ct;
                half8 bf = *(const half8*)&WmuT[(size_t)(cc * 16 + ar) * 128 + k];
#pragma unroll
                for (int rt = 0; rt < 3; ++rt)
                    acc[rt][ct] = __builtin_amdgcn_mfma_f32_16x16x32_f16(afr[rt], bf, acc[rt][ct], 0, 0, 0);
            }
        }
#pragma unroll
        for (int rt = 0; rt < 3; ++rt)
#pragma unroll
            for (int ct = 0; ct < 4; ++ct) {
                int col = (wave * 4 + ct) * 16 + ar;
#pragma unroll
                for (int r = 0; r < 4; ++r)
                    MM[(rt * 16 + kg * 4 + r) * 264 + col] = (h16)acc[rt][ct][r];
            }
    }
    __syncthreads();

    {
        int a = tid >> 4, fi = (tid & 15) * 8;
        const float* qp = q + (row0 + a) * 128 + fi;
        float4 q0 = *(const float4*)qp;
        float4 q1 = *(const float4*)(qp + 4);
        float qv[8] = {q0.x, q0.y, q0.z, q0.w, q1.x, q1.y, q1.z, q1.w};
#pragma unroll
        for (int jj = 0; jj < 8; ++jj) {
            int ff = fi + jj;
            float v0 = (float)MM[(a * 3 + 0) * 264 + ff];
            float v1 = (float)MM[(a * 3 + 1) * 264 + ff];
            float v2 = (float)MM[(a * 3 + 2) * 264 + ff];
            CT[a * 264 + 128 + ff] = (h16)sqrtf(v0 * v0 + v1 * v1 + v2 * v2 + 1e-8f);
            CT[a * 264 + ff] = (h16)qv[jj];
        }
    }
    __syncthreads();

    {
        f32x4 a1[2] = {};
        for (int ks = 0; ks < 256; ks += 32) {
            int k = ks + kg * 8;
            half8 af = *(const half8*)&CT[ar * 264 + k];
#pragma unroll
            for (int tt = 0; tt < 2; ++tt) {
                int t = wave * 2 + tt;
                half8 bf = *(const half8*)&W1t[(size_t)(t * 16 + ar) * 256 + k];
                a1[tt] = __builtin_amdgcn_mfma_f32_16x16x32_f16(af, bf, a1[tt], 0, 0, 0);
            }
        }
#pragma unroll
        for (int tt = 0; tt < 2; ++tt) {
            int col = (wave * 2 + tt) * 16 + ar;
            float bb = b1[col];
#pragma unroll
            for (int r = 0; r < 4; ++r)
                Hs[(kg * 4 + r) * 136 + col] = (h16)silu(a1[tt][r] + bb);
        }
    }
    __syncthreads();

    {
        f32x4 a2[6] = {};
        for (int ks = 0; ks < 128; ks += 32) {
            int k = ks + kg * 8;
            half8 af = *(const half8*)&Hs[ar * 136 + k];
#pragma unroll
            for (int tt = 0; tt < 6; ++tt) {
                int t = wave * 6 + tt;
                half8 bf = *(const half8*)&W2t[(size_t)(t * 16 + ar) * 128 + k];
                a2[tt] = __builtin_amdgcn_mfma_f32_16x16x32_f16(af, bf, a2[tt], 0, 0, 0);
            }
        }
#pragma unroll
        for (int tt = 0; tt < 6; ++tt) {
            int col = (wave * 6 + tt) * 16 + ar;
            float bb = b2[col];
#pragma unroll
            for (int r = 0; r < 4; ++r)
                XM[(kg * 4 + r) * 392 + col] = (h16)(a2[tt][r] + bb);
        }
    }
    __syncthreads();

    {
        int a = tid >> 4, fi = (tid & 15) * 8;
        size_t n = row0 + a;
#pragma unroll
        for (int jj = 0; jj < 8; ++jj) {
            int ff = fi + jj;
            float dq  = (float)XM[a * 392 + ff];
            float dm  = (float)XM[a * 392 + 128 + ff];
            float dqm = (float)XM[a * 392 + 256 + ff];
            float v0 = (float)MM[(a * 3 + 0) * 264 + ff], w0 = (float)MM[(a * 3 + 0) * 264 + 128 + ff];
            float v1 = (float)MM[(a * 3 + 1) * 264 + ff], w1 = (float)MM[(a * 3 + 1) * 264 + 128 + ff];
            float v2 = (float)MM[(a * 3 + 2) * 264 + ff], w2 = (float)MM[(a * 3 + 2) * 264 + 128 + ff];
            float sv = v0 * w0 + v1 * w1 + v2 * w2;
            float qn = q[n * 128 + ff] + dq + dqm * sv;
            q[n * 128 + ff] = qn;
            CT[a * 264 + ff] = (h16)qn;
            size_t b = n * 384 + ff;
            float m0 = mu[b] + dm * w0;
            float m1 = mu[b + 128] + dm * w1;
            float m2 = mu[b + 256] + dm * w2;
            mu[b] = m0; mu[b + 128] = m1; mu[b + 256] = m2;
            mu16w[b] = (h16)m0; mu16w[b + 128] = (h16)m1; mu16w[b + 256] = (h16)m2;
        }
    }
    if (!nW1t) return;
    __syncthreads();

    {
        f32x4 a1[2] = {};
        for (int ks = 0; ks < 128; ks += 32) {
            int k = ks + kg * 8;
            half8 af = *(const half8*)&CT[ar * 264 + k];
#pragma unroll
            for (int tt = 0; tt < 2; ++tt) {
                int t = wave * 2 + tt;
                half8 bf = *(const half8*)&nW1t[(size_t)(t * 16 + ar) * 128 + k];
                a1[tt] = __builtin_amdgcn_mfma_f32_16x16x32_f16(af, bf, a1[tt], 0, 0, 0);
            }
        }
#pragma unroll
        for (int tt = 0; tt < 2; ++tt) {
            int col = (wave * 2 + tt) * 16 + ar;
            float bb = nb1[col];
#pragma unroll
            for (int r = 0; r < 4; ++r)
                Hs[(kg * 4 + r) * 136 + col] = (h16)silu(a1[tt][r] + bb);
        }
        __syncthreads();
        f32x4 a2[6] = {};
        for (int ks = 0; ks < 128; ks += 32) {
            int k = ks + kg * 8;
            half8 af = *(const half8*)&Hs[ar * 136 + k];
#pragma unroll
            for (int tt = 0; tt < 6; ++tt) {
                int t = wave * 6 + tt;
                half8 bf = *(const half8*)&nW2t[(size_t)(t * 16 + ar) * 128 + k];
                a2[tt] = __builtin_amdgcn_mfma_f32_16x16x32_f16(af, bf, a2[tt], 0, 0, 0);
            }
        }
#pragma unroll
        for (int tt = 0; tt < 6; ++tt) {
            int col = (wave * 6 + tt) * 16 + ar;
            float bb = nb2[col];
#pragma unroll
            for (int r = 0; r < 4; ++r)
                x16[(row0 + kg * 4 + r) * 384 + col] = (h16)(a2[tt][r] + bb);
        }
    }
}

// ====== launch ======
extern "C" void kernel_launch(void* const* d_in, const int* in_sizes, int n_in,
                              void* d_out, int out_size, void* d_ws, size_t ws_size,
                              hipStream_t stream)
{
    const int*   Z       = (const int*)d_in[0];
    const float* R       = (const float*)d_in[1];
    const int*   idx_i   = (const int*)d_in[2];
    const int*   idx_j   = (const int*)d_in[3];
    const float* offsets = (const float*)d_in[4];
    const float* emb     = (const float*)d_in[5];
    const float* filt_W  = (const float*)d_in[6];
    const float* filt_b  = (const float*)d_in[7];
    const float* int_W1  = (const float*)d_in[8];
    const float* int_b1  = (const float*)d_in[9];
    const float* int_W2  = (const float*)d_in[10];
    const float* int_b2  = (const float*)d_in[11];
    const float* mix_Wmu = (const float*)d_in[12];
    const float* mix_W1  = (const float*)d_in[13];
    const float* mix_b1  = (const float*)d_in[14];
    const float* mix_W2  = (const float*)d_in[15];
    const float* mix_b2  = (const float*)d_in[16];

    float* q_out  = (float*)d_out;
    float* mu_out = (float*)d_out + (size_t)NA * FD;

    char* base = (char*)d_ws;
    size_t o = 0;
    auto alloc = [&](size_t bytes) -> void* {
        void* p = base + o;
        o += (bytes + 255) & ~(size_t)255;
        return p;
    };
    float* dir    = (float*)alloc((size_t)NE * 4 * 4);
    h16*   ph     = (h16*)alloc((size_t)NE * 32 * 2);
    int*   jdx    = (int*)alloc((size_t)NE * 4);
    h16*   x16    = (h16*)alloc((size_t)NA * 384 * 2);
    h16*   mu16a  = (h16*)alloc((size_t)NA * 384 * 2);
    h16*   mu16b  = (h16*)alloc((size_t)NA * 384 * 2);
    float* mu_ws  = (float*)alloc((size_t)NA * 384 * 4);
    h16*   W1t    = (h16*)alloc((size_t)3 * 128 * 128 * 2);
    h16*   W2t    = (h16*)alloc((size_t)3 * 384 * 128 * 2);
    h16*   WmuT   = (h16*)alloc((size_t)3 * 256 * 128 * 2);
    h16*   mW1t   = (h16*)alloc((size_t)3 * 128 * 256 * 2);
    h16*   mW2t   = (h16*)alloc((size_t)3 * 384 * 128 * 2);
    h16*   fwt    = (h16*)alloc((size_t)384 * 32 * 2);
    int*   row_st = (int*)alloc((size_t)(NA + 1) * 4);
    int*   cnt    = (int*)alloc((size_t)NA * 4);

    csr_kernel<<<(NA + 256) / 256, 256, 0, stream>>>(idx_i, row_st, cnt);
    setup_kernel<<<3137, 256, 0, stream>>>(R, idx_i, idx_j, offsets, dir, ph, jdx,
                                           row_st, cnt,
                                           int_W1, int_W2, mix_Wmu, mix_W1, mix_W2,
                                           W1t, W2t, WmuT, mW1t, mW2t,
                                           filt_W, filt_b, fwt);

    // iteration 0
    intmlp0_kernel<<<NA / 16, 256, 0, stream>>>(Z, emb, q_out,
                                                W1t, int_b1, W2t, int_b2, x16);
    edge_kernel<false><<<NA, 128, 0, stream>>>(dir, ph, fwt, row_st, cnt, jdx,
                                               x16, nullptr, nullptr, mu_out, mu16b, q_out);
    mixint_kernel<<<NA / 16, 256, 0, stream>>>(
        mu16b, WmuT, mW1t, mix_b1, mW2t, mix_b2, q_out, mu_out, mu16b,
        W1t + 16384, int_b1 + 128, W2t + 49152, int_b2 + 384, x16);

    // iteration 1
    edge_kernel<true><<<NA, 128, 0, stream>>>(dir, ph, fwt, row_st, cnt, jdx,
                                              x16, mu16b, mu_out, mu_ws, mu16a, q_out);
    mixint_kernel<<<NA / 16, 256, 0, stream>>>(
        mu16a, WmuT + 32768, mW1t + 32768, mix_b1 + 128, mW2t + 49152, mix_b2 + 384,
        q_out, mu_ws, mu16a,
        W1t + 32768, int_b1 + 256, W2t + 98304, int_b2 + 768, x16);

    // iteration 2
    edge_kernel<true><<<NA, 128, 0, stream>>>(dir, ph, fwt, row_st, cnt, jdx,
                                              x16, mu16a, mu_ws, mu_out, mu16b, q_out);
    mixint_kernel<<<NA / 16, 256, 0, stream>>>(
        mu16b, WmuT + 65536, mW1t + 65536, mix_b1 + 256, mW2t + 98304, mix_b2 + 768,
        q_out, mu_out, mu16b,
        nullptr, nullptr, nullptr, nullptr, nullptr);
}